// Round 14
// baseline (166.138 us; speedup 1.0000x reference)
//
#include <hip/hip_runtime.h>
#include <math.h>

#define C_LEN 2048
#define HALF  1024
#define OUTD  1536
#define NPIX  32768
#define LDSW  1088   // per-wave float2 slice: rows t*17 (pad) for T1/T4;
                     // flat [0,1024) for T2/FFT4-spec/middle/T5

#define FENCE() __builtin_amdgcn_sched_barrier(0)

// ======================= uv precompute (unchanged, verified) ================
__device__ __forceinline__ int SWZ(int idx) { return idx ^ ((idx >> 5) & 31); }

template<int DIR>
__device__ void fft2048(float* r0, float* i0, float* r1, float* i1, int t) {
    float *sr = r0, *si = i0, *dr = r1, *di = i1;
    const float TW = (float)DIR * 6.283185307179586f / 2048.0f;
    const float FD = (float)DIR;
    __syncthreads();
    #pragma unroll
    for (int b = 0; b < 4; ++b) {
        int t2 = t + b * 256;
        float ar = sr[SWZ(t2)],        ai = si[SWZ(t2)];
        float br = sr[SWZ(t2 + 1024)], bi = si[SWZ(t2 + 1024)];
        float sn, cs;
        sincosf(TW * (float)t2, &sn, &cs);
        float vr = ar - br, vi = ai - bi;
        int w0 = 2 * t2;
        dr[SWZ(w0)]     = ar + br;
        di[SWZ(w0)]     = ai + bi;
        dr[SWZ(w0 + 1)] = cs * vr - sn * vi;
        di[SWZ(w0 + 1)] = cs * vi + sn * vr;
    }
    { float* tp; tp = sr; sr = dr; dr = tp; tp = si; si = di; di = tp; }
    #pragma unroll
    for (int m = 2; m <= 512; m *= 4) {
        __syncthreads();
        #pragma unroll
        for (int b = 0; b < 2; ++b) {
            int t2 = t + b * 256;
            int jm = t2 & ~(m - 1);
            float a0r = sr[SWZ(t2)],        a0i = si[SWZ(t2)];
            float a1r = sr[SWZ(t2 + 512)],  a1i = si[SWZ(t2 + 512)];
            float a2r = sr[SWZ(t2 + 1024)], a2i = si[SWZ(t2 + 1024)];
            float a3r = sr[SWZ(t2 + 1536)], a3i = si[SWZ(t2 + 1536)];
            float s0r = a0r + a2r, s0i = a0i + a2i;
            float d0r = a0r - a2r, d0i = a0i - a2i;
            float s1r = a1r + a3r, s1i = a1i + a3i;
            float d1r = a1r - a3r, d1i = a1i - a3i;
            float A0r = s0r + s1r, A0i = s0i + s1i;
            float A2r = s0r - s1r, A2i = s0i - s1i;
            float A1r = d0r - FD * d1i, A1i = d0i + FD * d1r;
            float A3r = d0r + FD * d1i, A3i = d0i - FD * d1r;
            float s1w, c1w;
            sincosf(TW * (float)jm, &s1w, &c1w);
            float c2w = c1w * c1w - s1w * s1w, s2w = 2.0f * c1w * s1w;
            float c3w = c1w * c2w - s1w * s2w, s3w = c1w * s2w + s1w * c2w;
            int wb = t2 + 3 * jm;
            dr[SWZ(wb)]         = A0r;
            di[SWZ(wb)]         = A0i;
            dr[SWZ(wb + m)]     = c1w * A1r - s1w * A1i;
            di[SWZ(wb + m)]     = c1w * A1i + s1w * A1r;
            dr[SWZ(wb + 2 * m)] = c2w * A2r - s2w * A2i;
            di[SWZ(wb + 2 * m)] = c2w * A2i + s2w * A2r;
            dr[SWZ(wb + 3 * m)] = c3w * A3r - s3w * A3i;
            di[SWZ(wb + 3 * m)] = c3w * A3i + s3w * A3r;
        }
        { float* tp; tp = sr; sr = dr; dr = tp; tp = si; si = di; di = tp; }
    }
    __syncthreads();
}

__global__ __launch_bounds__(256)
void uv_kernel(const float* __restrict__ w1, const float* __restrict__ w2,
               float4* __restrict__ uv) {
    __shared__ float r0[C_LEN], i0[C_LEN], r1[C_LEN], i1[C_LEN];
    int t = threadIdx.x;
    #pragma unroll
    for (int k = 0; k < 8; ++k) {
        int e = t + k * 256;
        r0[SWZ(e)] = w1[e] * w2[e];
        i0[SWZ(e)] = 0.0f;
    }
    fft2048<-1>(r0, i0, r1, i1, t);
    #pragma unroll
    for (int b = 0; b < 4; ++b) {
        int k = t + b * 256;
        float w1r = r0[SWZ(k)],        w1i = i0[SWZ(k)];
        float w2r = r0[SWZ(k + 1024)], w2i = i0[SWZ(k + 1024)];
        float Sr = (w1r + w2r) * (1.0f / 4096.0f);
        float Si = (w1i + w2i) * (1.0f / 4096.0f);
        float Dr = (w1r - w2r) * (1.0f / 4096.0f);
        float Di = (w1i - w2i) * (1.0f / 4096.0f);
        float sn, cs;
        sincosf((6.283185307179586f / 2048.0f) * (float)k, &sn, &cs);
        float Er = cs * Dr - sn * Di, Ei = cs * Di + sn * Dr;
        float Fr = cs * Dr + sn * Di, Fi = cs * Di - sn * Dr;
        uv[k] = make_float4(Sr - Ei, Si + Er, Sr + Fi, Si - Fr);
    }
}

// ======================= in-place register FFT16 ============================
__device__ __forceinline__ void cm(float& or_, float& oi_, float ar, float ai,
                                   float br, float bi) {
    or_ = ar * br - ai * bi;
    oi_ = ar * bi + ai * br;
}

template<int S>
__device__ __forceinline__ void fft16_ip(float* xr, float* xi) {
    const float FS = (float)S;
    const float C1 = 0.9238795325112867f;
    const float S1 = 0.3826834323650898f;
    const float R2 = 0.7071067811865476f;
    #pragma unroll
    for (int n0 = 0; n0 < 4; ++n0) {
        float a0r = xr[n0],      a0i = xi[n0];
        float a1r = xr[n0 + 4],  a1i = xi[n0 + 4];
        float a2r = xr[n0 + 8],  a2i = xi[n0 + 8];
        float a3r = xr[n0 + 12], a3i = xi[n0 + 12];
        float t0r = a0r + a2r, t0i = a0i + a2i;
        float t1r = a0r - a2r, t1i = a0i - a2i;
        float t2r = a1r + a3r, t2i = a1i + a3i;
        float t3r = a1r - a3r, t3i = a1i - a3i;
        float y1r = t1r - FS * t3i, y1i = t1i + FS * t3r;
        float y2r = t0r - t2r,      y2i = t0i - t2i;
        float y3r = t1r + FS * t3i, y3i = t1i - FS * t3r;
        xr[n0] = t0r + t2r;  xi[n0] = t0i + t2i;
        if (n0 == 0) {
            xr[4]  = y1r; xi[4]  = y1i;
            xr[8]  = y2r; xi[8]  = y2i;
            xr[12] = y3r; xi[12] = y3i;
        } else if (n0 == 1) {
            cm(xr[5],  xi[5],  y1r, y1i, C1,  FS * S1);
            cm(xr[9],  xi[9],  y2r, y2i, R2,  FS * R2);
            cm(xr[13], xi[13], y3r, y3i, S1,  FS * C1);
        } else if (n0 == 2) {
            cm(xr[6],  xi[6],  y1r, y1i, R2,  FS * R2);
            xr[10] = -FS * y2i;  xi[10] = FS * y2r;
            cm(xr[14], xi[14], y3r, y3i, -R2, FS * R2);
        } else {
            cm(xr[7],  xi[7],  y1r, y1i, S1,  FS * C1);
            cm(xr[11], xi[11], y2r, y2i, -R2, FS * R2);
            cm(xr[15], xi[15], y3r, y3i, -C1, -FS * S1);
        }
    }
    #pragma unroll
    for (int k0 = 0; k0 < 4; ++k0) {
        float b0r = xr[4 * k0],     b0i = xi[4 * k0];
        float b1r = xr[4 * k0 + 1], b1i = xi[4 * k0 + 1];
        float b2r = xr[4 * k0 + 2], b2i = xi[4 * k0 + 2];
        float b3r = xr[4 * k0 + 3], b3i = xi[4 * k0 + 3];
        float t0r = b0r + b2r, t0i = b0i + b2i;
        float t1r = b0r - b2r, t1i = b0i - b2i;
        float t2r = b1r + b3r, t2i = b1i + b3i;
        float t3r = b1r - b3r, t3i = b1i - b3i;
        xr[4 * k0]     = t0r + t2r;      xi[4 * k0]     = t0i + t2i;
        xr[4 * k0 + 1] = t1r - FS * t3i; xi[4 * k0 + 1] = t1i + FS * t3r;
        xr[4 * k0 + 2] = t0r - t2r;      xi[4 * k0 + 2] = t0i - t2i;
        xr[4 * k0 + 3] = t1r + FS * t3i; xi[4 * k0 + 3] = t1i - FS * t3r;
    }
}

// Twiddle recurrence shared by both store helpers.
struct TwArr { float aR[4], aI[4], bR[4], bI[4]; };
__device__ __forceinline__ void tw_build(float th, TwArr& w) {
    float bs, bc;
    __sincosf(th, &bs, &bc);
    w.aR[0] = 1.f; w.aI[0] = 0.f;
    w.aR[1] = bc;  w.aI[1] = bs;
    w.aR[2] = bc * bc - bs * bs;           w.aI[2] = 2.f * bc * bs;
    w.aR[3] = w.aR[2] * bc - w.aI[2] * bs; w.aI[3] = w.aR[2] * bs + w.aI[2] * bc;
    w.bR[0] = 1.f; w.bI[0] = 0.f;
    w.bR[1] = w.aR[2] * w.aR[2] - w.aI[2] * w.aI[2];  w.bI[1] = 2.f * w.aR[2] * w.aI[2];
    w.bR[2] = w.bR[1] * w.bR[1] - w.bI[1] * w.bI[1];  w.bI[2] = 2.f * w.bR[1] * w.bI[1];
    w.bR[3] = w.bR[2] * w.bR[1] - w.bI[2] * w.bI[1];  w.bI[3] = w.bR[2] * w.bI[1] + w.bI[2] * w.bR[1];
}
__device__ __forceinline__ float2 tw_one(const float* vr, const float* vi,
                                         const TwArr& w, int c) {
    int p = ((c & 3) << 2) | (c >> 2);          // digit-swapped source slot
    float x0 = vr[p], y0 = vi[p];
    float x1 = x0 * w.aR[c & 3] - y0 * w.aI[c & 3];
    float y1 = x0 * w.aI[c & 3] + y0 * w.aR[c & 3];
    return make_float2(x1 * w.bR[c >> 2] - y1 * w.bI[c >> 2],
                       x1 * w.bI[c >> 2] + y1 * w.bR[c >> 2]);
}

// T1/T4: padded rows (stride 17), 16 x b64 stores (proven layout).
__device__ __forceinline__ void tw_store_pad(const float* vr, const float* vi,
                                             float2* row, float th) {
    TwArr w;
    tw_build(th, w);
    #pragma unroll
    for (int c = 0; c < 16; ++c)
        row[c] = tw_one(vr, vi, w, c);
}

// T2/T5: xor rows (stride 16), logical pairs (2u,2u+1) land at adjacent
// addresses ((m^cw)&~1) -> 8 x b128 stores at the bank floor. cw = writer's c.
__device__ __forceinline__ void tw_store_pair(const float* vr, const float* vi,
                                              float2* row, int cw, float th) {
    TwArr w;
    tw_build(th, w);
    #pragma unroll
    for (int u = 0; u < 8; ++u) {
        float2 v0 = tw_one(vr, vi, w, 2 * u);
        float2 v1 = tw_one(vr, vi, w, 2 * u + 1);
        int base = (2 * u) ^ (cw & ~1);         // == (m^cw) & ~1
        float4 F = (cw & 1) ? make_float4(v1.x, v1.y, v0.x, v0.y)
                            : make_float4(v0.x, v0.y, v1.x, v1.y);
        *reinterpret_cast<float4*>(row + base) = F;
    }
}

// ======================= main kernel: wave per pixel, 2 waves/block =========
// R8 skeleton (130us proven) with:
//  * T2w/T2r/T5w/T5r as paired b128 float4 ops (2 complex/op; addresses
//    (m^c)&~1 adjacent+16B aligned; verified 8-lane/granule = b128 floor).
//  * spec/out thread roles remapped (q=t>>4, c=t&15): specW becomes 16-lane
//    contiguous (bank floor) and global out writes coalesce in 128B runs.
//  * T1/T4 pad-17 layout and all math unchanged.
__global__ __launch_bounds__(128, 4)
void conv128(const float* __restrict__ x, const float4* __restrict__ uv,
             float2* __restrict__ out) {
    __shared__ float2 ldsAll[2 * LDSW];
    const int tid = threadIdx.x;
    const int t   = tid & 63;
    const int wid = tid >> 6;
    float2* lds = ldsAll + wid * LDSW;
    const size_t pix = ((size_t)blockIdx.x << 1) + wid;
    const float2* xp = reinterpret_cast<const float2*>(x) + pix * (size_t)HALF;

    const int f  = t & 3,  c2 = t >> 2;    // stage-2 coords (T1r/T2w/T4r/T5w)
    const int qq = t >> 4, cc = t & 15;    // spec/out coords (T2r/spec/T5r/out)

    float vr[16], vi[16];
    #pragma unroll
    for (int a = 0; a < 16; ++a) {
        float2 z = xp[(a << 6) + t];
        vr[a] = z.x; vi[a] = z.y;
    }

    // ---------------- forward ----------------
    fft16_ip<-1>(vr, vi);
    tw_store_pad(vr, vi, lds + t * 17,
                 (-6.283185307179586f / 1024.0f) * (float)t);       // T1w (pad)
    FENCE();
    {
        const float2* rp = lds + f * 17 + c2;                        // T1r (pad)
        #pragma unroll
        for (int e = 0; e < 16; ++e) {
            float2 z = rp[e * 68];                                   // (4e)*17
            vr[e] = z.x; vi[e] = z.y;
        }
        FENCE();
        fft16_ip<-1>(vr, vi);
        tw_store_pair(vr, vi, lds + (t << 4), c2,
                      (-6.283185307179586f / 64.0f) * (float)f);     // T2w b128
    }
    FENCE();
    {
        float dr[16], di[16];
        #pragma unroll
        for (int f2 = 0; f2 < 4; ++f2) {
            #pragma unroll
            for (int u = 0; u < 2; ++u) {                            // T2r b128
                int row  = (cc << 2) + f2;
                int base = ((qq << 2) + (u << 1)) ^ (cc & ~1);
                float4 F = *reinterpret_cast<const float4*>(lds + (row << 4) + base);
                int i0 = f2 * 4 + 2 * u;
                if (cc & 1) {
                    dr[i0]     = F.z; di[i0]     = F.w;
                    dr[i0 + 1] = F.x; di[i0 + 1] = F.y;
                } else {
                    dr[i0]     = F.x; di[i0]     = F.y;
                    dr[i0 + 1] = F.z; di[i0 + 1] = F.w;
                }
            }
        }
        FENCE();
        #pragma unroll
        for (int s = 0; s < 4; ++s) {                                // FFT4 fwd
            float ar = dr[0 + s],  ai = di[0 + s];
            float br = dr[4 + s],  bi = di[4 + s];
            float cr = dr[8 + s],  ci = di[8 + s];
            float er = dr[12 + s], ei = di[12 + s];
            float t0r = ar + cr, t0i = ai + ci;
            float t1r = ar - cr, t1i = ai - ci;
            float t2r = br + er, t2i = bi + ei;
            float t3r = br - er, t3i = bi - ei;
            int kb = cc + (qq << 6) + (s << 4);
            lds[kb]       = make_float2(t0r + t2r, t0i + t2i);       // p=0
            lds[kb + 256] = make_float2(t1r + t3i, t1i - t3r);       // p=1 (S=-1)
            lds[kb + 512] = make_float2(t0r - t2r, t0i - t2i);       // p=2
            lds[kb + 768] = make_float2(t1r - t3i, t1i + t3r);       // p=3
        }
    }
    FENCE();

    // ------------- middle (rfft unpack * Wf * repack) ------------
    #pragma unroll
    for (int a = 0; a < 16; ++a) {
        int k = (a << 6) + t;
        float2 Za = lds[k];
        float2 Zm = lds[(HALF - k) & (HALF - 1)];
        float4 u  = uv[k];
        float Ar = Za.x + Zm.x, Ai = Za.y - Zm.y;
        float Br = Za.x - Zm.x, Bi = Za.y + Zm.y;
        vr[a] = Ar * u.x - Ai * u.y + Br * u.z - Bi * u.w;
        vi[a] = Ar * u.y + Ai * u.x + Br * u.w + Bi * u.z;
    }
    FENCE();

    // ---------------- inverse ----------------
    fft16_ip<1>(vr, vi);
    tw_store_pad(vr, vi, lds + t * 17,
                 (6.283185307179586f / 1024.0f) * (float)t);         // T4w (pad)
    FENCE();
    {
        const float2* rp = lds + f * 17 + c2;                        // T4r (pad)
        #pragma unroll
        for (int e = 0; e < 16; ++e) {
            float2 z = rp[e * 68];
            vr[e] = z.x; vi[e] = z.y;
        }
        FENCE();
        fft16_ip<1>(vr, vi);
        tw_store_pair(vr, vi, lds + (t << 4), c2,
                      (6.283185307179586f / 64.0f) * (float)f);      // T5w b128
    }
    FENCE();
    {
        float dr[16], di[16];
        #pragma unroll
        for (int f2 = 0; f2 < 4; ++f2) {
            #pragma unroll
            for (int u = 0; u < 2; ++u) {                            // T5r b128
                int row  = (cc << 2) + f2;
                int base = ((qq << 2) + (u << 1)) ^ (cc & ~1);
                float4 F = *reinterpret_cast<const float4*>(lds + (row << 4) + base);
                int i0 = f2 * 4 + 2 * u;
                if (cc & 1) {
                    dr[i0]     = F.z; di[i0]     = F.w;
                    dr[i0 + 1] = F.x; di[i0 + 1] = F.y;
                } else {
                    dr[i0]     = F.x; di[i0]     = F.y;
                    dr[i0 + 1] = F.z; di[i0 + 1] = F.w;
                }
            }
        }
        float2* op = out + pix * (size_t)(OUTD / 2);
        #pragma unroll
        for (int s = 0; s < 4; ++s) {                                // FFT4 inv
            float ar = dr[0 + s],  ai = di[0 + s];
            float br = dr[4 + s],  bi = di[4 + s];
            float cr = dr[8 + s],  ci = di[8 + s];
            float er = dr[12 + s], ei = di[12 + s];
            float t0r = ar + cr, t0i = ai + ci;
            float t1r = ar - cr, t1i = ai - ci;
            float t2r = br + er, t2i = bi + ei;
            float t3r = br - er, t3i = bi - ei;
            int nb = cc + (qq << 6) + (s << 4);
            op[nb]       = make_float2(t0r + t2r, t0i + t2i);        // p=0
            op[nb + 256] = make_float2(t1r - t3i, t1i + t3r);        // p=1 (S=+1)
            op[nb + 512] = make_float2(t0r - t2r, t0i - t2i);        // p=2
            // p=3 (n >= 768) not stored
        }
    }
}

extern "C" void kernel_launch(void* const* d_in, const int* in_sizes, int n_in,
                              void* d_out, int out_size, void* d_ws, size_t ws_size,
                              hipStream_t stream) {
    const float* x  = (const float*)d_in[0];
    const float* w1 = (const float*)d_in[1];
    const float* w2 = (const float*)d_in[2];
    float2* out = (float2*)d_out;
    float4* uv  = (float4*)d_ws;          // 1024 float4 = 16 KB

    hipLaunchKernelGGL(uv_kernel, dim3(1), dim3(256), 0, stream, w1, w2, uv);
    hipLaunchKernelGGL(conv128, dim3(NPIX / 2), dim3(128), 0, stream, x, uv, out);
}

// Round 15
// 129.537 us; speedup vs baseline: 1.2825x; 1.2825x over previous
//
#include <hip/hip_runtime.h>
#include <math.h>

#define C_LEN 2048
#define HALF  1024
#define OUTD  1536
#define NPIX  32768
#define LDSW  1088   // per-block float4 slice: 64 rows x 17 (pad) for T1/T4;
                     // flat [0,1024) reused by T2/FFT4/middle/T5
                     // float4 slot = (A.re, A.im, B.re, B.im)

#define FENCE() __builtin_amdgcn_sched_barrier(0)

// ======================= uv precompute (unchanged, verified) ================
__device__ __forceinline__ int SWZ(int idx) { return idx ^ ((idx >> 5) & 31); }

template<int DIR>
__device__ void fft2048(float* r0, float* i0, float* r1, float* i1, int t) {
    float *sr = r0, *si = i0, *dr = r1, *di = i1;
    const float TW = (float)DIR * 6.283185307179586f / 2048.0f;
    const float FD = (float)DIR;
    __syncthreads();
    #pragma unroll
    for (int b = 0; b < 4; ++b) {
        int t2 = t + b * 256;
        float ar = sr[SWZ(t2)],        ai = si[SWZ(t2)];
        float br = sr[SWZ(t2 + 1024)], bi = si[SWZ(t2 + 1024)];
        float sn, cs;
        sincosf(TW * (float)t2, &sn, &cs);
        float vr = ar - br, vi = ai - bi;
        int w0 = 2 * t2;
        dr[SWZ(w0)]     = ar + br;
        di[SWZ(w0)]     = ai + bi;
        dr[SWZ(w0 + 1)] = cs * vr - sn * vi;
        di[SWZ(w0 + 1)] = cs * vi + sn * vr;
    }
    { float* tp; tp = sr; sr = dr; dr = tp; tp = si; si = di; di = tp; }
    #pragma unroll
    for (int m = 2; m <= 512; m *= 4) {
        __syncthreads();
        #pragma unroll
        for (int b = 0; b < 2; ++b) {
            int t2 = t + b * 256;
            int jm = t2 & ~(m - 1);
            float a0r = sr[SWZ(t2)],        a0i = si[SWZ(t2)];
            float a1r = sr[SWZ(t2 + 512)],  a1i = si[SWZ(t2 + 512)];
            float a2r = sr[SWZ(t2 + 1024)], a2i = si[SWZ(t2 + 1024)];
            float a3r = sr[SWZ(t2 + 1536)], a3i = si[SWZ(t2 + 1536)];
            float s0r = a0r + a2r, s0i = a0i + a2i;
            float d0r = a0r - a2r, d0i = a0i - a2i;
            float s1r = a1r + a3r, s1i = a1i + a3i;
            float d1r = a1r - a3r, d1i = a1i - a3i;
            float A0r = s0r + s1r, A0i = s0i + s1i;
            float A2r = s0r - s1r, A2i = s0i - s1i;
            float A1r = d0r - FD * d1i, A1i = d0i + FD * d1r;
            float A3r = d0r + FD * d1i, A3i = d0i - FD * d1r;
            float s1w, c1w;
            sincosf(TW * (float)jm, &s1w, &c1w);
            float c2w = c1w * c1w - s1w * s1w, s2w = 2.0f * c1w * s1w;
            float c3w = c1w * c2w - s1w * s2w, s3w = c1w * s2w + s1w * c2w;
            int wb = t2 + 3 * jm;
            dr[SWZ(wb)]         = A0r;
            di[SWZ(wb)]         = A0i;
            dr[SWZ(wb + m)]     = c1w * A1r - s1w * A1i;
            di[SWZ(wb + m)]     = c1w * A1i + s1w * A1r;
            dr[SWZ(wb + 2 * m)] = c2w * A2r - s2w * A2i;
            di[SWZ(wb + 2 * m)] = c2w * A2i + s2w * A2r;
            dr[SWZ(wb + 3 * m)] = c3w * A3r - s3w * A3i;
            di[SWZ(wb + 3 * m)] = c3w * A3i + s3w * A3r;
        }
        { float* tp; tp = sr; sr = dr; dr = tp; tp = si; si = di; di = tp; }
    }
    __syncthreads();
}

__global__ __launch_bounds__(256)
void uv_kernel(const float* __restrict__ w1, const float* __restrict__ w2,
               float4* __restrict__ uv) {
    __shared__ float r0[C_LEN], i0[C_LEN], r1[C_LEN], i1[C_LEN];
    int t = threadIdx.x;
    #pragma unroll
    for (int k = 0; k < 8; ++k) {
        int e = t + k * 256;
        r0[SWZ(e)] = w1[e] * w2[e];
        i0[SWZ(e)] = 0.0f;
    }
    fft2048<-1>(r0, i0, r1, i1, t);
    #pragma unroll
    for (int b = 0; b < 4; ++b) {
        int k = t + b * 256;
        float w1r = r0[SWZ(k)],        w1i = i0[SWZ(k)];
        float w2r = r0[SWZ(k + 1024)], w2i = i0[SWZ(k + 1024)];
        float Sr = (w1r + w2r) * (1.0f / 4096.0f);
        float Si = (w1i + w2i) * (1.0f / 4096.0f);
        float Dr = (w1r - w2r) * (1.0f / 4096.0f);
        float Di = (w1i - w2i) * (1.0f / 4096.0f);
        float sn, cs;
        sincosf((6.283185307179586f / 2048.0f) * (float)k, &sn, &cs);
        float Er = cs * Dr - sn * Di, Ei = cs * Di + sn * Dr;
        float Fr = cs * Dr + sn * Di, Fi = cs * Di - sn * Dr;
        uv[k] = make_float4(Sr - Ei, Si + Er, Sr + Fi, Si - Fr);
    }
}

// ======================= in-place register FFT16 ============================
__device__ __forceinline__ void cm(float& or_, float& oi_, float ar, float ai,
                                   float br, float bi) {
    or_ = ar * br - ai * bi;
    oi_ = ar * bi + ai * br;
}

// In-place 16-pt DFT (sign S). Output digit-swapped:
//   slot[4*(k&3) + (k>>2)] = X[k],  X[k] = sum_n x[n] e^{S*2*pi*i*n*k/16}
template<int S>
__device__ __forceinline__ void fft16_ip(float* xr, float* xi) {
    const float FS = (float)S;
    const float C1 = 0.9238795325112867f;
    const float S1 = 0.3826834323650898f;
    const float R2 = 0.7071067811865476f;
    #pragma unroll
    for (int n0 = 0; n0 < 4; ++n0) {
        float a0r = xr[n0],      a0i = xi[n0];
        float a1r = xr[n0 + 4],  a1i = xi[n0 + 4];
        float a2r = xr[n0 + 8],  a2i = xi[n0 + 8];
        float a3r = xr[n0 + 12], a3i = xi[n0 + 12];
        float t0r = a0r + a2r, t0i = a0i + a2i;
        float t1r = a0r - a2r, t1i = a0i - a2i;
        float t2r = a1r + a3r, t2i = a1i + a3i;
        float t3r = a1r - a3r, t3i = a1i - a3i;
        float y1r = t1r - FS * t3i, y1i = t1i + FS * t3r;
        float y2r = t0r - t2r,      y2i = t0i - t2i;
        float y3r = t1r + FS * t3i, y3i = t1i - FS * t3r;
        xr[n0] = t0r + t2r;  xi[n0] = t0i + t2i;
        if (n0 == 0) {
            xr[4]  = y1r; xi[4]  = y1i;
            xr[8]  = y2r; xi[8]  = y2i;
            xr[12] = y3r; xi[12] = y3i;
        } else if (n0 == 1) {
            cm(xr[5],  xi[5],  y1r, y1i, C1,  FS * S1);
            cm(xr[9],  xi[9],  y2r, y2i, R2,  FS * R2);
            cm(xr[13], xi[13], y3r, y3i, S1,  FS * C1);
        } else if (n0 == 2) {
            cm(xr[6],  xi[6],  y1r, y1i, R2,  FS * R2);
            xr[10] = -FS * y2i;  xi[10] = FS * y2r;
            cm(xr[14], xi[14], y3r, y3i, -R2, FS * R2);
        } else {
            cm(xr[7],  xi[7],  y1r, y1i, S1,  FS * C1);
            cm(xr[11], xi[11], y2r, y2i, -R2, FS * R2);
            cm(xr[15], xi[15], y3r, y3i, -C1, -FS * S1);
        }
    }
    #pragma unroll
    for (int k0 = 0; k0 < 4; ++k0) {
        float b0r = xr[4 * k0],     b0i = xi[4 * k0];
        float b1r = xr[4 * k0 + 1], b1i = xi[4 * k0 + 1];
        float b2r = xr[4 * k0 + 2], b2i = xi[4 * k0 + 2];
        float b3r = xr[4 * k0 + 3], b3i = xi[4 * k0 + 3];
        float t0r = b0r + b2r, t0i = b0i + b2i;
        float t1r = b0r - b2r, t1i = b0i - b2i;
        float t2r = b1r + b3r, t2i = b1i + b3i;
        float t3r = b1r - b3r, t3i = b1i - b3i;
        xr[4 * k0]     = t0r + t2r;      xi[4 * k0]     = t0i + t2i;
        xr[4 * k0 + 1] = t1r - FS * t3i; xi[4 * k0 + 1] = t1i + FS * t3r;
        xr[4 * k0 + 2] = t0r - t2r;      xi[4 * k0 + 2] = t0i - t2i;
        xr[4 * k0 + 3] = t1r + FS * t3i; xi[4 * k0 + 3] = t1i - FS * t3r;
    }
}

// Fused twiddle + transposed LDS store, TWO pixels (A,B) sharing the twiddle
// recurrence. w^c = e^{i*c*th} combined once; applied to both pixels; stored
// as float4 (A.re, A.im, B.re, B.im) at row[c ^ xorv]. Reads digit-swapped
// slot p.
__device__ __forceinline__ void tw_store2(const float* vrA, const float* viA,
                                          const float* vrB, const float* viB,
                                          float4* row, int xorv, float th) {
    float bs, bc;
    __sincosf(th, &bs, &bc);
    float aR[4], aI[4], bR[4], bI[4];
    aR[0] = 1.f; aI[0] = 0.f;
    aR[1] = bc;  aI[1] = bs;
    aR[2] = bc * bc - bs * bs;          aI[2] = 2.f * bc * bs;
    aR[3] = aR[2] * bc - aI[2] * bs;    aI[3] = aR[2] * bs + aI[2] * bc;
    bR[0] = 1.f; bI[0] = 0.f;
    bR[1] = aR[2] * aR[2] - aI[2] * aI[2];  bI[1] = 2.f * aR[2] * aI[2];
    bR[2] = bR[1] * bR[1] - bI[1] * bI[1];  bI[2] = 2.f * bR[1] * bI[1];
    bR[3] = bR[2] * bR[1] - bI[2] * bI[1];  bI[3] = bR[2] * bI[1] + bI[2] * bR[1];
    #pragma unroll
    for (int c = 0; c < 16; ++c) {
        int p = ((c & 3) << 2) | (c >> 2);
        float wr = aR[c & 3] * bR[c >> 2] - aI[c & 3] * bI[c >> 2];
        float wi = aR[c & 3] * bI[c >> 2] + aI[c & 3] * bR[c >> 2];
        float xA = vrA[p] * wr - viA[p] * wi;
        float yA = vrA[p] * wi + viA[p] * wr;
        float xB = vrB[p] * wr - viB[p] * wi;
        float yB = vrB[p] * wi + viB[p] * wr;
        row[c ^ xorv] = make_float4(xA, yA, xB, yB);
    }
}

// ======================= main kernel: 2 pixels per wave =====================
// One 64-thread block = one wave = pixels (2*bid, 2*bid+1) interleaved in a
// single float4 LDS slice. Best measured config (R9: 128.6us). The two
// dependence chains hide each other's latency; twiddle recurrence, sincos
// and uv loads shared between pixels.
__global__ __launch_bounds__(64, 2)
void conv64x2(const float* __restrict__ x, const float4* __restrict__ uv,
              float2* __restrict__ out) {
    __shared__ float4 lds[LDSW];
    const int t = threadIdx.x;
    const size_t pixA = (size_t)blockIdx.x << 1;
    const float2* xpA = reinterpret_cast<const float2*>(x) + pixA * (size_t)HALF;
    const float2* xpB = xpA + HALF;

    float vrA[16], viA[16], vrB[16], viB[16];
    #pragma unroll
    for (int a = 0; a < 16; ++a) {
        float2 zA = xpA[(a << 6) + t];
        float2 zB = xpB[(a << 6) + t];
        vrA[a] = zA.x; viA[a] = zA.y;
        vrB[a] = zB.x; viB[a] = zB.y;
    }

    // ---------------- forward ----------------
    fft16_ip<-1>(vrA, viA);
    fft16_ip<-1>(vrB, viB);
    tw_store2(vrA, viA, vrB, viB, lds + t * 17, 0,
              (-6.283185307179586f / 1024.0f) * (float)t);          // T1w (pad)
    FENCE();
    {
        const int f = t & 3, c = t >> 2;
        const float4* rp = lds + f * 17 + c;                        // T1r (pad)
        #pragma unroll
        for (int e = 0; e < 16; ++e) {
            float4 z = rp[e * 68];                                  // (4e)*17
            vrA[e] = z.x; viA[e] = z.y; vrB[e] = z.z; viB[e] = z.w;
        }
        FENCE();
        fft16_ip<-1>(vrA, viA);
        fft16_ip<-1>(vrB, viB);
        tw_store2(vrA, viA, vrB, viB, lds + (t << 4), c,
                  (-6.283185307179586f / 64.0f) * (float)f);        // T2w (xor)
    }
    FENCE();
    {
        const int q = t & 3, c = t >> 2;
        float drA[16], diA[16], drB[16], diB[16];
        #pragma unroll
        for (int f2 = 0; f2 < 4; ++f2) {
            #pragma unroll
            for (int s = 0; s < 4; ++s) {                           // T2r (xor)
                int wrow = (c << 2) + f2;
                float4 z = lds[(wrow << 4) + (((q << 2) + s) ^ c)];
                drA[f2 * 4 + s] = z.x; diA[f2 * 4 + s] = z.y;
                drB[f2 * 4 + s] = z.z; diB[f2 * 4 + s] = z.w;
            }
        }
        FENCE();
        #pragma unroll
        for (int s = 0; s < 4; ++s) {                               // FFT4 fwd
            int kb = c + (((q << 2) + s) << 4);
            {
                float ar = drA[0 + s],  ai = diA[0 + s];
                float br = drA[4 + s],  bi = diA[4 + s];
                float cr = drA[8 + s],  ci = diA[8 + s];
                float er = drA[12 + s], ei = diA[12 + s];
                float t0r = ar + cr, t0i = ai + ci;
                float t1r = ar - cr, t1i = ai - ci;
                float t2r = br + er, t2i = bi + ei;
                float t3r = br - er, t3i = bi - ei;
                float Br = drB[0 + s],  Bi = diB[0 + s];
                float Cr = drB[4 + s],  Ci = diB[4 + s];
                float Dr = drB[8 + s],  Di = diB[8 + s];
                float Er = drB[12 + s], Ei = diB[12 + s];
                float u0r = Br + Dr, u0i = Bi + Di;
                float u1r = Br - Dr, u1i = Bi - Di;
                float u2r = Cr + Er, u2i = Ci + Ei;
                float u3r = Cr - Er, u3i = Ci - Ei;
                lds[kb]       = make_float4(t0r + t2r, t0i + t2i,
                                            u0r + u2r, u0i + u2i);  // p=0
                lds[kb + 256] = make_float4(t1r + t3i, t1i - t3r,
                                            u1r + u3i, u1i - u3r);  // p=1 (S=-1)
                lds[kb + 512] = make_float4(t0r - t2r, t0i - t2i,
                                            u0r - u2r, u0i - u2i);  // p=2
                lds[kb + 768] = make_float4(t1r - t3i, t1i + t3r,
                                            u1r - u3i, u1i + u3r);  // p=3
            }
        }
    }
    FENCE();

    // ------------- middle (rfft unpack * Wf * repack), uv shared ------------
    #pragma unroll
    for (int a = 0; a < 16; ++a) {
        int k = (a << 6) + t;
        float4 Za = lds[k];
        float4 Zm = lds[(HALF - k) & (HALF - 1)];
        float4 u  = uv[k];
        {
            float Ar = Za.x + Zm.x, Ai = Za.y - Zm.y;
            float Br = Za.x - Zm.x, Bi = Za.y + Zm.y;
            vrA[a] = Ar * u.x - Ai * u.y + Br * u.z - Bi * u.w;
            viA[a] = Ar * u.y + Ai * u.x + Br * u.w + Bi * u.z;
        }
        {
            float Ar = Za.z + Zm.z, Ai = Za.w - Zm.w;
            float Br = Za.z - Zm.z, Bi = Za.w + Zm.w;
            vrB[a] = Ar * u.x - Ai * u.y + Br * u.z - Bi * u.w;
            viB[a] = Ar * u.y + Ai * u.x + Br * u.w + Bi * u.z;
        }
    }
    FENCE();

    // ---------------- inverse ----------------
    fft16_ip<1>(vrA, viA);
    fft16_ip<1>(vrB, viB);
    tw_store2(vrA, viA, vrB, viB, lds + t * 17, 0,
              (6.283185307179586f / 1024.0f) * (float)t);           // T4w (pad)
    FENCE();
    {
        const int f = t & 3, c = t >> 2;
        const float4* rp = lds + f * 17 + c;                        // T4r (pad)
        #pragma unroll
        for (int e = 0; e < 16; ++e) {
            float4 z = rp[e * 68];
            vrA[e] = z.x; viA[e] = z.y; vrB[e] = z.z; viB[e] = z.w;
        }
        FENCE();
        fft16_ip<1>(vrA, viA);
        fft16_ip<1>(vrB, viB);
        tw_store2(vrA, viA, vrB, viB, lds + (t << 4), c,
                  (6.283185307179586f / 64.0f) * (float)f);         // T5w (xor)
    }
    FENCE();
    {
        const int q = t & 3, c = t >> 2;
        float drA[16], diA[16], drB[16], diB[16];
        #pragma unroll
        for (int f2 = 0; f2 < 4; ++f2) {
            #pragma unroll
            for (int s = 0; s < 4; ++s) {                           // T5r (xor)
                int wrow = (c << 2) + f2;
                float4 z = lds[(wrow << 4) + (((q << 2) + s) ^ c)];
                drA[f2 * 4 + s] = z.x; diA[f2 * 4 + s] = z.y;
                drB[f2 * 4 + s] = z.z; diB[f2 * 4 + s] = z.w;
            }
        }
        float2* opA = out + pixA * (size_t)(OUTD / 2);
        float2* opB = opA + (OUTD / 2);
        #pragma unroll
        for (int s = 0; s < 4; ++s) {                               // FFT4 inv
            int nb = c + (((q << 2) + s) << 4);
            {   // pixel A
                float ar = drA[0 + s],  ai = diA[0 + s];
                float br = drA[4 + s],  bi = diA[4 + s];
                float cr = drA[8 + s],  ci = diA[8 + s];
                float er = drA[12 + s], ei = diA[12 + s];
                float t0r = ar + cr, t0i = ai + ci;
                float t1r = ar - cr, t1i = ai - ci;
                float t2r = br + er, t2i = bi + ei;
                float t3r = br - er, t3i = bi - ei;
                opA[nb]       = make_float2(t0r + t2r, t0i + t2i);  // p=0
                opA[nb + 256] = make_float2(t1r - t3i, t1i + t3r);  // p=1 (S=+1)
                opA[nb + 512] = make_float2(t0r - t2r, t0i - t2i);  // p=2
            }
            {   // pixel B
                float ar = drB[0 + s],  ai = diB[0 + s];
                float br = drB[4 + s],  bi = diB[4 + s];
                float cr = drB[8 + s],  ci = diB[8 + s];
                float er = drB[12 + s], ei = diB[12 + s];
                float t0r = ar + cr, t0i = ai + ci;
                float t1r = ar - cr, t1i = ai - ci;
                float t2r = br + er, t2i = bi + ei;
                float t3r = br - er, t3i = bi - ei;
                opB[nb]       = make_float2(t0r + t2r, t0i + t2i);  // p=0
                opB[nb + 256] = make_float2(t1r - t3i, t1i + t3r);  // p=1 (S=+1)
                opB[nb + 512] = make_float2(t0r - t2r, t0i - t2i);  // p=2
            }
            // p=3 (n >= 768) not stored
        }
    }
}

extern "C" void kernel_launch(void* const* d_in, const int* in_sizes, int n_in,
                              void* d_out, int out_size, void* d_ws, size_t ws_size,
                              hipStream_t stream) {
    const float* x  = (const float*)d_in[0];
    const float* w1 = (const float*)d_in[1];
    const float* w2 = (const float*)d_in[2];
    float2* out = (float2*)d_out;
    float4* uv  = (float4*)d_ws;          // 1024 float4 = 16 KB

    hipLaunchKernelGGL(uv_kernel, dim3(1), dim3(256), 0, stream, w1, w2, uv);
    hipLaunchKernelGGL(conv64x2, dim3(NPIX / 2), dim3(64), 0, stream, x, uv, out);
}